// Round 1
// baseline (122.085 us; speedup 1.0000x reference)
//
#include <hip/hip_runtime.h>

#define N_NODES 100000
#define N_EDGES 1600000
#define IN_DIM  128
#define HID_DIM 128
#define OUT_DIM 256

// capacities for edges into node 0 and the unique frontier set S
#define ECAP 1024
#define SCAP 1056   // >= ECAP + 1

// ---------------- init workspace ----------------
__global__ void k_init(int* __restrict__ deg, int* __restrict__ flag,
                       int* __restrict__ ctrl, float* __restrict__ acc) {
    int i = blockIdx.x * blockDim.x + threadIdx.x;
    int stride = gridDim.x * blockDim.x;
    for (int j = i; j < N_NODES; j += stride) { deg[j] = 0; flag[j] = -1; }
    for (int j = i; j < SCAP * IN_DIM; j += stride) acc[j] = 0.f;
    if (i < 16) ctrl[i] = 0;
}

// ---------------- pass 1: in-degree of every node + record edges into node 0 ----------------
__global__ void k_deg(const int* __restrict__ src, const int* __restrict__ dst,
                      int* __restrict__ deg, int* __restrict__ ctrl,
                      int* __restrict__ e0src) {
    int i = blockIdx.x * blockDim.x + threadIdx.x;
    int stride = gridDim.x * blockDim.x;
    for (int e = i; e < N_EDGES; e += stride) {
        int d = dst[e];
        atomicAdd(&deg[d], 1);
        if (d == 0) {
            int p = atomicAdd(&ctrl[0], 1);
            if (p < ECAP) e0src[p] = src[e];
        }
    }
}

// ---------------- pass 2 (1 thread): build unique frontier S, index it via flag[] ----------------
__global__ void k_buildS(int* __restrict__ ctrl, const int* __restrict__ e0src,
                         int* __restrict__ flag, int* __restrict__ S_node,
                         const int* __restrict__ deg, float* __restrict__ dinvS) {
    int cnt0 = ctrl[0]; if (cnt0 > ECAP) cnt0 = ECAP;
    int nS = 0;
    for (int i = 0; i <= cnt0; i++) {
        int n = (i < cnt0) ? e0src[i] : 0;  // include node 0 (self-loop of layer 2)
        if (flag[n] < 0) {
            flag[n] = nS;
            S_node[nS] = n;
            dinvS[nS] = rsqrtf((float)(deg[n] + 1));  // +1: self-loop
            nS++;
        }
    }
    ctrl[1] = nS;
    ctrl[2] = cnt0;
}

// ---------------- pass 3: accumulate  acc[k] += x[src] * dinv[src]*dinv[dst]  for dst in S ----------------
__global__ void k_gather(const int* __restrict__ src, const int* __restrict__ dst,
                         const int* __restrict__ flag, const int* __restrict__ deg,
                         const float* __restrict__ dinvS, const float* __restrict__ x,
                         float* __restrict__ acc) {
    int i = blockIdx.x * blockDim.x + threadIdx.x;
    int stride = gridDim.x * blockDim.x;
    for (int e = i; e < N_EDGES; e += stride) {
        int d = dst[e];
        int k = flag[d];            // 400 KB array: L2-resident random read
        if (k >= 0) {
            int s = src[e];
            float norm = rsqrtf((float)(deg[s] + 1)) * dinvS[k];
            const float* xs = x + (size_t)s * IN_DIM;
            float* a = acc + k * IN_DIM;
            #pragma unroll 4
            for (int j = 0; j < IN_DIM; j++) atomicAdd(&a[j], xs[j] * norm);
        }
    }
}

// ---------------- per-s: add self-loop, v @ W1 + b1, relu -> h1 ----------------
__global__ void k_layer1(const int* __restrict__ ctrl, const int* __restrict__ S_node,
                         const float* __restrict__ dinvS, const float* __restrict__ x,
                         const float* __restrict__ acc, const float* __restrict__ W1,
                         const float* __restrict__ b1, float* __restrict__ h1) {
    int k = blockIdx.x;
    if (k >= ctrl[1]) return;
    __shared__ float v[IN_DIM];
    int t = threadIdx.x;  // 128 threads
    int n = S_node[k];
    float di = dinvS[k];
    v[t] = acc[k * IN_DIM + t] + x[(size_t)n * IN_DIM + t] * di * di;
    __syncthreads();
    float sum = b1[t];
    #pragma unroll 8
    for (int j = 0; j < IN_DIM; j++) sum += v[j] * W1[j * HID_DIM + t];
    h1[k * HID_DIM + t] = fmaxf(sum, 0.f);
}

// ---------------- layer 2 for node 0 only: msg2 -> msg2 @ W2 + b2 ----------------
__global__ void k_layer2(const int* __restrict__ ctrl, const int* __restrict__ e0src,
                         const int* __restrict__ flag, const int* __restrict__ deg,
                         const float* __restrict__ h1, const float* __restrict__ W2,
                         const float* __restrict__ b2, float* __restrict__ out) {
    __shared__ float m[HID_DIM];
    int t = threadIdx.x;  // 256 threads
    int cnt0 = ctrl[2];
    float dinv0 = rsqrtf((float)(deg[0] + 1));
    if (t < HID_DIM) {
        float s = h1[flag[0] * HID_DIM + t] * dinv0 * dinv0;  // self-loop
        for (int i = 0; i < cnt0; i++) {
            int n = e0src[i];
            s += h1[flag[n] * HID_DIM + t] * rsqrtf((float)(deg[n] + 1)) * dinv0;
        }
        m[t] = s;
    }
    __syncthreads();
    float sum = b2[t];
    #pragma unroll 8
    for (int j = 0; j < HID_DIM; j++) sum += m[j] * W2[j * OUT_DIM + t];
    out[t] = sum;
}

extern "C" void kernel_launch(void* const* d_in, const int* in_sizes, int n_in,
                              void* d_out, int out_size, void* d_ws, size_t ws_size,
                              hipStream_t stream) {
    const float* x  = (const float*)d_in[0];
    const int*   ei = (const int*)d_in[1];           // edge_index flattened [2, E]
    const float* W1 = (const float*)d_in[2];
    const float* b1 = (const float*)d_in[3];
    const float* W2 = (const float*)d_in[4];
    const float* b2 = (const float*)d_in[5];
    float* out = (float*)d_out;

    const int* src = ei;            // edge_index[0]
    const int* dst = ei + N_EDGES;  // edge_index[1]

    // workspace carve-up (all 4-byte aligned); total ~1.9 MB
    char* w = (char*)d_ws;
    int*   deg    = (int*)w;                 w += sizeof(int) * N_NODES;
    int*   flag   = (int*)w;                 w += sizeof(int) * N_NODES;
    int*   ctrl   = (int*)w;                 w += sizeof(int) * 16;
    int*   e0src  = (int*)w;                 w += sizeof(int) * ECAP;
    int*   S_node = (int*)w;                 w += sizeof(int) * SCAP;
    float* dinvS  = (float*)w;               w += sizeof(float) * SCAP;
    float* acc    = (float*)w;               w += sizeof(float) * SCAP * IN_DIM;
    float* h1     = (float*)w;               w += sizeof(float) * SCAP * HID_DIM;

    k_init<<<1024, 256, 0, stream>>>(deg, flag, ctrl, acc);
    k_deg<<<2048, 256, 0, stream>>>(src, dst, deg, ctrl, e0src);
    k_buildS<<<1, 1, 0, stream>>>(ctrl, e0src, flag, S_node, deg, dinvS);
    k_gather<<<2048, 256, 0, stream>>>(src, dst, flag, deg, dinvS, x, acc);
    k_layer1<<<SCAP, IN_DIM, 0, stream>>>(ctrl, S_node, dinvS, x, acc, W1, b1, h1);
    k_layer2<<<1, OUT_DIM, 0, stream>>>(ctrl, e0src, flag, deg, h1, W2, b2, out);
}